// Round 1
// baseline (363.852 us; speedup 1.0000x reference)
//
#include <hip/hip_runtime.h>

// FlowNetC fused: conv3x3(x1,w) -> f1 ; conv3x3(x2,w) -> f2 ;
// out[b,k,h,w] = mean_c f1[b,c,h,w] * f2[b,c,h+dy,w+dx], dy,dx in {-2,0,2}
// B=16, C=3, H=W=512, K=9. Output f32, 16*9*512*512 elems.

#define BATCH 16
#define HH 512
#define WW 512
#define TS 32          // output tile edge
#define XT 38          // x2 halo tile edge (TS + 6)
#define XP 40          // padded LDS row stride for x tiles
#define FT 36          // f2 tile edge (TS + 4)
#define FP 38          // padded LDS row stride for f2 tile

__global__ __launch_bounds__(256)
void flownetc_fused_kernel(const float* __restrict__ x1,
                           const float* __restrict__ x2,
                           const float* __restrict__ cw,
                           float* __restrict__ out) {
    __shared__ float s_w[81];                 // OIHW 3x3x3x3
    __shared__ float s_x[3][XT][XP];          // x halo staging (reused x2 then x1)
    __shared__ float s_f2[3][FT][FP];         // conv output f2 tile (+/-2 halo)

    const int tileX = blockIdx.x;
    const int tileY = blockIdx.y;
    const int bi    = blockIdx.z;
    const int ox0 = tileX * TS;
    const int oy0 = tileY * TS;
    const int tid = threadIdx.x;

    if (tid < 81) s_w[tid] = cw[tid];

    // ---- stage x2 halo: rows oy0-3 .. oy0+34, cols ox0-3 .. ox0+34 ----
    const float* x2b = x2 + (size_t)bi * 3 * HH * WW;
    for (int i = tid; i < 3 * XT * XT; i += 256) {
        int c   = i / (XT * XT);
        int r   = (i / XT) % XT;
        int col = i % XT;
        int gy = oy0 - 3 + r;
        int gx = ox0 - 3 + col;
        float v = 0.f;
        if ((unsigned)gy < HH && (unsigned)gx < WW)
            v = x2b[(c * HH + gy) * WW + gx];
        s_x[c][r][col] = v;
    }
    __syncthreads();

    // ---- compute f2 tile (origin oy0-2, ox0-2); zero where outside image ----
    // (reference zero-pads f2 itself for the correlation, so OOB f2 == 0)
    for (int i = tid; i < 3 * FT * FT; i += 256) {
        int c   = i / (FT * FT);
        int r   = (i / FT) % FT;
        int col = i % FT;
        int gy = oy0 - 2 + r;
        int gx = ox0 - 2 + col;
        float acc = 0.f;
        if ((unsigned)gy < HH && (unsigned)gx < WW) {
            #pragma unroll
            for (int ci = 0; ci < 3; ++ci)
                #pragma unroll
                for (int ky = 0; ky < 3; ++ky)
                    #pragma unroll
                    for (int kx = 0; kx < 3; ++kx)
                        acc += s_w[((c * 3 + ci) * 3 + ky) * 3 + kx]
                             * s_x[ci][r + ky][col + kx];
        }
        s_f2[c][r][col] = acc;
    }
    __syncthreads();

    // ---- stage x1 tile: rows oy0-1 .. oy0+32 (34x34), reuse s_x ----
    const float* x1b = x1 + (size_t)bi * 3 * HH * WW;
    for (int i = tid; i < 3 * 34 * 34; i += 256) {
        int c   = i / (34 * 34);
        int r   = (i / 34) % 34;
        int col = i % 34;
        int gy = oy0 - 1 + r;
        int gx = ox0 - 1 + col;
        float v = 0.f;
        if ((unsigned)gy < HH && (unsigned)gx < WW)
            v = x1b[(c * HH + gy) * WW + gx];
        s_x[c][r][col] = v;
    }
    __syncthreads();

    // ---- per-thread: 4 pixels, compute f1 in regs, correlate, store ----
    const int tx = tid & 31;        // column within tile
    const int ty = tid >> 5;        // row group (8 rows, x4 strided)
    float* outb = out + (size_t)bi * 9 * HH * WW;

    #pragma unroll
    for (int j = 0; j < 4; ++j) {
        const int py = ty + 8 * j;
        // f1 at tile pixel (py, tx): x1 staged with origin (oy0-1, ox0-1)
        float f1c[3];
        #pragma unroll
        for (int c = 0; c < 3; ++c) {
            float acc = 0.f;
            #pragma unroll
            for (int ci = 0; ci < 3; ++ci)
                #pragma unroll
                for (int ky = 0; ky < 3; ++ky)
                    #pragma unroll
                    for (int kx = 0; kx < 3; ++kx)
                        acc += s_w[((c * 3 + ci) * 3 + ky) * 3 + kx]
                             * s_x[ci][py + ky][tx + kx];
            f1c[c] = acc;
        }
        const int gy = oy0 + py;
        const int gx = ox0 + tx;
        #pragma unroll
        for (int k = 0; k < 9; ++k) {
            const int dy = (k / 3) * 2 - 2;
            const int dx = (k % 3) * 2 - 2;
            const float v = (f1c[0] * s_f2[0][py + 2 + dy][tx + 2 + dx]
                           + f1c[1] * s_f2[1][py + 2 + dy][tx + 2 + dx]
                           + f1c[2] * s_f2[2][py + 2 + dy][tx + 2 + dx]) * (1.f / 3.f);
            outb[((size_t)k * HH + gy) * WW + gx] = v;
        }
    }
}

extern "C" void kernel_launch(void* const* d_in, const int* in_sizes, int n_in,
                              void* d_out, int out_size, void* d_ws, size_t ws_size,
                              hipStream_t stream) {
    const float* x1 = (const float*)d_in[0];
    const float* x2 = (const float*)d_in[1];
    const float* cw = (const float*)d_in[2];
    float* out = (float*)d_out;

    dim3 grid(WW / TS, HH / TS, BATCH);   // 16 x 16 x 16 = 4096 blocks
    flownetc_fused_kernel<<<grid, 256, 0, stream>>>(x1, x2, cw, out);
}

// Round 2
// 127.549 us; speedup vs baseline: 2.8526x; 2.8526x over previous
//
#include <hip/hip_runtime.h>

// FlowNetC fused: f1=conv3x3(x1,w), f2=conv3x3(x2,w),
// out[b,k,h,w] = mean_c f1[b,c,h,w]*f2[b,c,h+dy,w+dx], dy,dx in {-2,0,2}
// B=16,C=3,H=W=512,K=9. f32 output.
//
// R2: async global_load_lds staging (x1+x2 issued together, one vmcnt drain
// at the barrier), 2 barrier phases instead of 3. Linear unpadded LDS layout
// for the staged tiles so lane->LDS mapping matches global_load_lds's
// wave-uniform-base + lane*4 semantics; OOB border elems zeroed via disjoint
// ds_writes.

#define BATCH 16
#define HH 512
#define WW 512
#define TS 32
#define XT2 38                 // x2 halo tile edge (TS+6)
#define N2 (3*XT2*XT2)         // 4332
#define XT1 34                 // x1 halo tile edge (TS+2)
#define N1 (3*XT1*XT1)         // 3468
#define FT 36                  // f2 tile edge (TS+4)
#define FP 38                  // padded stride for f2 tile

typedef const __attribute__((address_space(1))) void* gas_ptr;
typedef __attribute__((address_space(3))) void* las_ptr;

__global__ __launch_bounds__(256)
void flownetc_fused_kernel(const float* __restrict__ x1,
                           const float* __restrict__ x2,
                           const float* __restrict__ cw,
                           float* __restrict__ out) {
    __shared__ float s_w[81];
    __shared__ float s_x2[N2];          // linear [3][38][38]
    __shared__ float s_x1[N1];          // linear [3][34][34]
    __shared__ float s_f2[3][FT][FP];

    const int tid = threadIdx.x;
    const int ox0 = blockIdx.x * TS;
    const int oy0 = blockIdx.y * TS;
    const int bi  = blockIdx.z;

    if (tid < 81) s_w[tid] = cw[tid];

    // ---- async stage x2 halo (origin oy0-3, ox0-3), 38x38x3 ----
    const float* x2b = x2 + (size_t)bi * 3 * HH * WW;
    #pragma unroll
    for (int it = 0; it < 17; ++it) {
        int idx = it * 256 + tid;
        if (idx < N2) {
            int c   = idx / (XT2 * XT2);
            int rem = idx - c * (XT2 * XT2);
            int r   = rem / XT2;
            int col = rem - r * XT2;
            int gy = oy0 - 3 + r;
            int gx = ox0 - 3 + col;
            float* ldsbase = s_x2 + (idx & ~63);   // wave-uniform
            if ((unsigned)gy < HH && (unsigned)gx < WW) {
                __builtin_amdgcn_global_load_lds(
                    (gas_ptr)(x2b + (size_t)(c * HH + gy) * WW + gx),
                    (las_ptr)ldsbase, 4, 0, 0);
            } else {
                s_x2[idx] = 0.f;                   // disjoint addr, no race
            }
        }
    }

    // ---- async stage x1 halo (origin oy0-1, ox0-1), 34x34x3 ----
    const float* x1b = x1 + (size_t)bi * 3 * HH * WW;
    #pragma unroll
    for (int it = 0; it < 14; ++it) {
        int idx = it * 256 + tid;
        if (idx < N1) {
            int c   = idx / (XT1 * XT1);
            int rem = idx - c * (XT1 * XT1);
            int r   = rem / XT1;
            int col = rem - r * XT1;
            int gy = oy0 - 1 + r;
            int gx = ox0 - 1 + col;
            float* ldsbase = s_x1 + (idx & ~63);   // wave-uniform
            if ((unsigned)gy < HH && (unsigned)gx < WW) {
                __builtin_amdgcn_global_load_lds(
                    (gas_ptr)(x1b + (size_t)(c * HH + gy) * WW + gx),
                    (las_ptr)ldsbase, 4, 0, 0);
            } else {
                s_x1[idx] = 0.f;
            }
        }
    }

    __syncthreads();   // drains vmcnt+lgkmcnt: all staging complete

    // ---- f1 for this thread's 4 pixels, in registers ----
    const int tx = tid & 31;
    const int ty = tid >> 5;
    float f1r[4][3];
    #pragma unroll
    for (int j = 0; j < 4; ++j) {
        const int py = ty + 8 * j;
        #pragma unroll
        for (int c = 0; c < 3; ++c) {
            float acc = 0.f;
            #pragma unroll
            for (int ci = 0; ci < 3; ++ci)
                #pragma unroll
                for (int ky = 0; ky < 3; ++ky)
                    #pragma unroll
                    for (int kx = 0; kx < 3; ++kx)
                        acc += s_w[((c * 3 + ci) * 3 + ky) * 3 + kx]
                             * s_x1[(ci * XT1 + py + ky) * XT1 + tx + kx];
            f1r[j][c] = acc;
        }
    }

    // ---- f2 tile (origin oy0-2, ox0-2), 36x36x3 -> s_f2 ----
    for (int it = 0; it < 16; ++it) {
        int i = it * 256 + tid;
        if (i < 3 * FT * FT) {
            int c   = i / (FT * FT);
            int rem = i - c * (FT * FT);
            int r   = rem / FT;
            int col = rem - r * FT;
            int gy = oy0 - 2 + r;
            int gx = ox0 - 2 + col;
            float acc = 0.f;
            if ((unsigned)gy < HH && (unsigned)gx < WW) {
                #pragma unroll
                for (int ci = 0; ci < 3; ++ci)
                    #pragma unroll
                    for (int ky = 0; ky < 3; ++ky)
                        #pragma unroll
                        for (int kx = 0; kx < 3; ++kx)
                            acc += s_w[((c * 3 + ci) * 3 + ky) * 3 + kx]
                                 * s_x2[(ci * XT2 + r + ky) * XT2 + col + kx];
            }
            s_f2[c][r][col] = acc;
        }
    }
    __syncthreads();

    // ---- correlation + store ----
    float* outb = out + (size_t)bi * 9 * HH * WW;
    #pragma unroll
    for (int j = 0; j < 4; ++j) {
        const int py = ty + 8 * j;
        const int gy = oy0 + py;
        const int gx = ox0 + tx;
        #pragma unroll
        for (int k = 0; k < 9; ++k) {
            const int ry = py + (k / 3) * 2;   // py+2+dy, dy=(k/3)*2-2
            const int rx = tx + (k % 3) * 2;
            const float v = (f1r[j][0] * s_f2[0][ry][rx]
                           + f1r[j][1] * s_f2[1][ry][rx]
                           + f1r[j][2] * s_f2[2][ry][rx]) * (1.f / 3.f);
            outb[((size_t)k * HH + gy) * WW + gx] = v;
        }
    }
}

extern "C" void kernel_launch(void* const* d_in, const int* in_sizes, int n_in,
                              void* d_out, int out_size, void* d_ws, size_t ws_size,
                              hipStream_t stream) {
    const float* x1 = (const float*)d_in[0];
    const float* x2 = (const float*)d_in[1];
    const float* cw = (const float*)d_in[2];
    float* out = (float*)d_out;

    dim3 grid(WW / TS, HH / TS, BATCH);   // 16 x 16 x 16 = 4096 blocks
    flownetc_fused_kernel<<<grid, 256, 0, stream>>>(x1, x2, cw, out);
}

// Round 4
// 62.032 us; speedup vs baseline: 5.8656x; 2.0562x over previous
//
#include <hip/hip_runtime.h>

// FlowNetC fused: f1=conv3x3(x1,w), f2=conv3x3(x2,w),
// out[b,k,h,w] = mean_c f1[b,c,h,w]*f2[b,c,h+dy,w+dx], dy,dx in {-2,0,2}
// B=16,C=3,H=W=512,K=9. f32.
//
// R4 = R3 with ext_vector f32x4 for the nontemporal store (HIP float4 is a
// class type the builtin rejects).
// R3: weights via scalar loads (uniform const-index reads of cw -> s_load,
// no LDS), run-of-4 sliding-window convs with ds_read_b128/b64 (aligned
// strides 40/36/40), width-16 global_load_lds staging with scalar border
// fallback, dwordx4 nontemporal stores, XCD-contiguous block swizzle.

#define HH 512
#define WW 512
#define TS 32
#define X2R 38
#define X2S 40              // staged cols (stride), 160B-aligned rows
#define X1R 34
#define X1S 36              // 144B-aligned rows
#define F2R 36
#define F2S 40
#define N2 (3*X2R*X2S)      // 4560 words
#define N1 (3*X1R*X1S)      // 3672 words
#define NC2 (3*X2R*(X2S/4)) // 1140 16B chunks
#define NC1 (3*X1R*(X1S/4)) // 918

typedef const __attribute__((address_space(1))) void* gas_ptr;
typedef __attribute__((address_space(3))) void* las_ptr;
typedef float f32x4 __attribute__((ext_vector_type(4)));

__global__ __launch_bounds__(256)
void flownetc_fused_kernel(const float* __restrict__ x1,
                           const float* __restrict__ x2,
                           const float* __restrict__ cw,
                           float* __restrict__ out) {
  __shared__ __align__(16) float s_x2[N2];
  __shared__ __align__(16) float s_x1[N1];
  __shared__ __align__(16) float s_f2[3*F2R*F2S];

  const int tid = threadIdx.x;
  // XCD-contiguous swizzle: 4096 blocks / 8 XCDs = 512 contiguous each
  const int bid = blockIdx.x;
  const int f   = (bid & 7) * 512 + (bid >> 3);
  const int ox0 = (f & 15) * TS;
  const int oy0 = ((f >> 4) & 15) * TS;
  const int bi  = f >> 8;

  const float* x2b = x2 + (size_t)bi * 3 * HH * WW;
  const float* x1b = x1 + (size_t)bi * 3 * HH * WW;

  // ---- stage x2 [3][38][40] origin (oy0-3, ox0-3), 16B chunks ----
  for (int q = tid; q < NC2; q += 256) {
    const int colq = q % (X2S / 4);
    const int rp   = q / (X2S / 4);
    const int r    = rp % X2R;
    const int c    = rp / X2R;
    const int gy   = oy0 - 3 + r;
    const int gx0  = ox0 - 3 + colq * 4;
    const float* src = x2b + (size_t)(c * HH + gy) * WW + gx0;
    if ((unsigned)gy < HH && (unsigned)gx0 <= (WW - 4)) {
      __builtin_amdgcn_global_load_lds((gas_ptr)src,
          (las_ptr)(s_x2 + ((q & ~63) << 2)), 16, 0, 0);
    } else {
      const bool rowok = (unsigned)gy < HH;
      float4 v;
      v.x = (rowok && (unsigned)(gx0 + 0) < WW) ? src[0] : 0.f;
      v.y = (rowok && (unsigned)(gx0 + 1) < WW) ? src[1] : 0.f;
      v.z = (rowok && (unsigned)(gx0 + 2) < WW) ? src[2] : 0.f;
      v.w = (rowok && (unsigned)(gx0 + 3) < WW) ? src[3] : 0.f;
      *reinterpret_cast<float4*>(&s_x2[q * 4]) = v;
    }
  }
  // ---- stage x1 [3][34][36] origin (oy0-1, ox0-1) ----
  for (int q = tid; q < NC1; q += 256) {
    const int colq = q % (X1S / 4);
    const int rp   = q / (X1S / 4);
    const int r    = rp % X1R;
    const int c    = rp / X1R;
    const int gy   = oy0 - 1 + r;
    const int gx0  = ox0 - 1 + colq * 4;
    const float* src = x1b + (size_t)(c * HH + gy) * WW + gx0;
    if ((unsigned)gy < HH && (unsigned)gx0 <= (WW - 4)) {
      __builtin_amdgcn_global_load_lds((gas_ptr)src,
          (las_ptr)(s_x1 + ((q & ~63) << 2)), 16, 0, 0);
    } else {
      const bool rowok = (unsigned)gy < HH;
      float4 v;
      v.x = (rowok && (unsigned)(gx0 + 0) < WW) ? src[0] : 0.f;
      v.y = (rowok && (unsigned)(gx0 + 1) < WW) ? src[1] : 0.f;
      v.z = (rowok && (unsigned)(gx0 + 2) < WW) ? src[2] : 0.f;
      v.w = (rowok && (unsigned)(gx0 + 3) < WW) ? src[3] : 0.f;
      *reinterpret_cast<float4*>(&s_x1[q * 4]) = v;
    }
  }
  __syncthreads();   // drain staging (vmcnt + lgkmcnt)

  // ---- f2 conv: 324 run-units (row r 0..35, 9 col-segments of 4),
  //      each computes all 3 c_out (weight reads amortized, s_load) ----
  for (int run = tid; run < 324; run += 256) {
    const int col0 = (run % 9) * 4;
    const int r    = run / 9;
    float acc[3][4] = {};
    #pragma unroll
    for (int ci = 0; ci < 3; ++ci) {
      float win[3][6];
      #pragma unroll
      for (int ky = 0; ky < 3; ++ky) {
        const float* base = &s_x2[(ci * X2R + r + ky) * X2S + col0];
        const float4 a  = *reinterpret_cast<const float4*>(base);
        const float2 b2 = *reinterpret_cast<const float2*>(base + 4);
        win[ky][0] = a.x; win[ky][1] = a.y; win[ky][2] = a.z; win[ky][3] = a.w;
        win[ky][4] = b2.x; win[ky][5] = b2.y;
      }
      #pragma unroll
      for (int co = 0; co < 3; ++co)
        #pragma unroll
        for (int ky = 0; ky < 3; ++ky)
          #pragma unroll
          for (int kx = 0; kx < 3; ++kx) {
            const float w = cw[((co * 3 + ci) * 3 + ky) * 3 + kx]; // uniform -> s_load
            #pragma unroll
            for (int j = 0; j < 4; ++j)
              acc[co][j] += w * win[ky][j + kx];
          }
    }
    // f2 itself is zero-padded by the correlation: zero outside image
    const int gy = oy0 - 2 + r;
    #pragma unroll
    for (int j = 0; j < 4; ++j) {
      const int gx = ox0 - 2 + col0 + j;
      if (!((unsigned)gy < HH && (unsigned)gx < WW)) {
        acc[0][j] = 0.f; acc[1][j] = 0.f; acc[2][j] = 0.f;
      }
    }
    #pragma unroll
    for (int co = 0; co < 3; ++co)
      *reinterpret_cast<float4*>(&s_f2[(co * F2R + r) * F2S + col0]) =
          make_float4(acc[co][0], acc[co][1], acc[co][2], acc[co][3]);
  }

  // ---- f1 for this thread's run of 4 pixels (row py, cols px0..px0+3) ----
  const int py  = tid >> 3;
  const int px0 = (tid & 7) << 2;
  float f1r[3][4] = {};
  #pragma unroll
  for (int ci = 0; ci < 3; ++ci) {
    float win[3][6];
    #pragma unroll
    for (int ky = 0; ky < 3; ++ky) {
      const float* base = &s_x1[(ci * X1R + py + ky) * X1S + px0];
      const float4 a  = *reinterpret_cast<const float4*>(base);
      const float2 b2 = *reinterpret_cast<const float2*>(base + 4);
      win[ky][0] = a.x; win[ky][1] = a.y; win[ky][2] = a.z; win[ky][3] = a.w;
      win[ky][4] = b2.x; win[ky][5] = b2.y;
    }
    #pragma unroll
    for (int co = 0; co < 3; ++co)
      #pragma unroll
      for (int ky = 0; ky < 3; ++ky)
        #pragma unroll
        for (int kx = 0; kx < 3; ++kx) {
          const float w = cw[((co * 3 + ci) * 3 + ky) * 3 + kx];
          #pragma unroll
          for (int j = 0; j < 4; ++j)
            f1r[co][j] += w * win[ky][j + kx];
        }
  }
  __syncthreads();

  // ---- correlation + stores (dwordx4, nontemporal) ----
  float* outp = out + ((size_t)bi * 9 * HH + (oy0 + py)) * WW + ox0 + px0;
  #pragma unroll
  for (int dyi = 0; dyi < 3; ++dyi) {
    float rv[3][8];
    #pragma unroll
    for (int c = 0; c < 3; ++c) {
      const float* base = &s_f2[(c * F2R + py + dyi * 2) * F2S + px0];
      const float4 a = *reinterpret_cast<const float4*>(base);
      const float4 b = *reinterpret_cast<const float4*>(base + 4);
      rv[c][0] = a.x; rv[c][1] = a.y; rv[c][2] = a.z; rv[c][3] = a.w;
      rv[c][4] = b.x; rv[c][5] = b.y; rv[c][6] = b.z; rv[c][7] = b.w;
    }
    #pragma unroll
    for (int dxi = 0; dxi < 3; ++dxi) {
      const int s = dxi * 2;
      f32x4 o;
      o.x = (f1r[0][0]*rv[0][s+0] + f1r[1][0]*rv[1][s+0] + f1r[2][0]*rv[2][s+0]) * (1.f/3.f);
      o.y = (f1r[0][1]*rv[0][s+1] + f1r[1][1]*rv[1][s+1] + f1r[2][1]*rv[2][s+1]) * (1.f/3.f);
      o.z = (f1r[0][2]*rv[0][s+2] + f1r[1][2]*rv[1][s+2] + f1r[2][2]*rv[2][s+2]) * (1.f/3.f);
      o.w = (f1r[0][3]*rv[0][s+3] + f1r[1][3]*rv[1][s+3] + f1r[2][3]*rv[2][s+3]) * (1.f/3.f);
      __builtin_nontemporal_store(o,
          reinterpret_cast<f32x4*>(outp + (size_t)(dyi * 3 + dxi) * HH * WW));
    }
  }
}

extern "C" void kernel_launch(void* const* d_in, const int* in_sizes, int n_in,
                              void* d_out, int out_size, void* d_ws, size_t ws_size,
                              hipStream_t stream) {
  const float* x1 = (const float*)d_in[0];
  const float* x2 = (const float*)d_in[1];
  const float* cw = (const float*)d_in[2];
  float* out = (float*)d_out;

  flownetc_fused_kernel<<<dim3(4096), 256, 0, stream>>>(x1, x2, cw, out);
}

// Round 5
// 59.045 us; speedup vs baseline: 6.1623x; 1.0506x over previous
//
#include <hip/hip_runtime.h>

// FlowNetC fused: f1=conv3x3(x1,w), f2=conv3x3(x2,w),
// out[b,k,h,w] = mean_c f1[b,c,h,w]*f2[b,c,h+dy,w+dx], dy,dx in {-2,0,2}
// B=16,C=3,H=W=512,K=9. f32.
//
// R5: LDS overlay for occupancy. s_x1 staging and s_f2 tile share one
// buffer (s_ov): phase B computes f1 AND f2 into registers (reading
// s_x1/s_x2), phase C writes f2 regs into s_ov over the dead x1 data.
// LDS 50.7KB -> 35.5KB => 4 blocks/CU (16 waves, 50% occ) vs 3.
// Everything else per R4: scalar-pipe weights, width-16 global_load_lds
// staging, run-of-4 sliding windows, dwordx4 nontemporal stores, XCD swizzle.

#define HH 512
#define WW 512
#define TS 32
#define X2R 38
#define X2S 40              // x2 stride, rows 160B-aligned
#define X1R 34
#define X1S 36              // x1 stride, rows 144B-aligned
#define F2R 36
#define F2S 40
#define N2 (3*X2R*X2S)      // 4560 words
#define N1 (3*X1R*X1S)      // 3672 words
#define NF (3*F2R*F2S)      // 4320 words (overlay region size)
#define NC2 (3*X2R*(X2S/4)) // 1140 16B chunks
#define NC1 (3*X1R*(X1S/4)) // 918

typedef const __attribute__((address_space(1))) void* gas_ptr;
typedef __attribute__((address_space(3))) void* las_ptr;
typedef float f32x4 __attribute__((ext_vector_type(4)));

__global__ __launch_bounds__(256)
void flownetc_fused_kernel(const float* __restrict__ x1,
                           const float* __restrict__ x2,
                           const float* __restrict__ cw,
                           float* __restrict__ out) {
  __shared__ __align__(16) float s_x2[N2];
  __shared__ __align__(16) float s_ov[NF];   // x1 staging (first N1) then f2

  const int tid = threadIdx.x;
  // XCD-contiguous swizzle: 4096 blocks / 8 XCDs = 512 contiguous each
  const int bid = blockIdx.x;
  const int f   = (bid & 7) * 512 + (bid >> 3);
  const int ox0 = (f & 15) * TS;
  const int oy0 = ((f >> 4) & 15) * TS;
  const int bi  = f >> 8;

  const float* x2b = x2 + (size_t)bi * 3 * HH * WW;
  const float* x1b = x1 + (size_t)bi * 3 * HH * WW;

  // ---- stage x2 [3][38][40] origin (oy0-3, ox0-3), 16B chunks ----
  for (int q = tid; q < NC2; q += 256) {
    const int colq = q % (X2S / 4);
    const int rp   = q / (X2S / 4);
    const int r    = rp % X2R;
    const int c    = rp / X2R;
    const int gy   = oy0 - 3 + r;
    const int gx0  = ox0 - 3 + colq * 4;
    const float* src = x2b + (size_t)(c * HH + gy) * WW + gx0;
    if ((unsigned)gy < HH && (unsigned)gx0 <= (WW - 4)) {
      __builtin_amdgcn_global_load_lds((gas_ptr)src,
          (las_ptr)(s_x2 + ((q & ~63) << 2)), 16, 0, 0);
    } else {
      const bool rowok = (unsigned)gy < HH;
      float4 v;
      v.x = (rowok && (unsigned)(gx0 + 0) < WW) ? src[0] : 0.f;
      v.y = (rowok && (unsigned)(gx0 + 1) < WW) ? src[1] : 0.f;
      v.z = (rowok && (unsigned)(gx0 + 2) < WW) ? src[2] : 0.f;
      v.w = (rowok && (unsigned)(gx0 + 3) < WW) ? src[3] : 0.f;
      *reinterpret_cast<float4*>(&s_x2[q * 4]) = v;
    }
  }
  // ---- stage x1 [3][34][36] origin (oy0-1, ox0-1) into s_ov ----
  for (int q = tid; q < NC1; q += 256) {
    const int colq = q % (X1S / 4);
    const int rp   = q / (X1S / 4);
    const int r    = rp % X1R;
    const int c    = rp / X1R;
    const int gy   = oy0 - 1 + r;
    const int gx0  = ox0 - 1 + colq * 4;
    const float* src = x1b + (size_t)(c * HH + gy) * WW + gx0;
    if ((unsigned)gy < HH && (unsigned)gx0 <= (WW - 4)) {
      __builtin_amdgcn_global_load_lds((gas_ptr)src,
          (las_ptr)(s_ov + ((q & ~63) << 2)), 16, 0, 0);
    } else {
      const bool rowok = (unsigned)gy < HH;
      float4 v;
      v.x = (rowok && (unsigned)(gx0 + 0) < WW) ? src[0] : 0.f;
      v.y = (rowok && (unsigned)(gx0 + 1) < WW) ? src[1] : 0.f;
      v.z = (rowok && (unsigned)(gx0 + 2) < WW) ? src[2] : 0.f;
      v.w = (rowok && (unsigned)(gx0 + 3) < WW) ? src[3] : 0.f;
      *reinterpret_cast<float4*>(&s_ov[q * 4]) = v;
    }
  }
  __syncthreads();   // staging complete

  // ---- phase B: f2 (regs) from s_x2, f1 (regs) from s_ov-as-x1 ----
  // f2 run-unit: row r (0..35), col segment of 4; 324 units over 256 threads.
  auto f2unit = [&](int run, float acc[3][4]) {
    const int col0 = (run % 9) * 4;
    const int r    = run / 9;
    #pragma unroll
    for (int co = 0; co < 3; ++co)
      #pragma unroll
      for (int j = 0; j < 4; ++j) acc[co][j] = 0.f;
    #pragma unroll
    for (int ci = 0; ci < 3; ++ci) {
      float win[3][6];
      #pragma unroll
      for (int ky = 0; ky < 3; ++ky) {
        const float* base = &s_x2[(ci * X2R + r + ky) * X2S + col0];
        const float4 a  = *reinterpret_cast<const float4*>(base);
        const float2 b2 = *reinterpret_cast<const float2*>(base + 4);
        win[ky][0] = a.x; win[ky][1] = a.y; win[ky][2] = a.z; win[ky][3] = a.w;
        win[ky][4] = b2.x; win[ky][5] = b2.y;
      }
      #pragma unroll
      for (int co = 0; co < 3; ++co)
        #pragma unroll
        for (int ky = 0; ky < 3; ++ky)
          #pragma unroll
          for (int kx = 0; kx < 3; ++kx) {
            const float w = cw[((co * 3 + ci) * 3 + ky) * 3 + kx]; // uniform -> SGPR
            #pragma unroll
            for (int j = 0; j < 4; ++j)
              acc[co][j] += w * win[ky][j + kx];
          }
    }
    // correlation zero-pads f2: zero outside the image
    const int gy = oy0 - 2 + r;
    #pragma unroll
    for (int j = 0; j < 4; ++j) {
      const int gx = ox0 - 2 + col0 + j;
      if (!((unsigned)gy < HH && (unsigned)gx < WW)) {
        acc[0][j] = 0.f; acc[1][j] = 0.f; acc[2][j] = 0.f;
      }
    }
  };

  float acc0[3][4];
  float acc1[3][4];
  f2unit(tid, acc0);
  if (tid < 324 - 256) f2unit(tid + 256, acc1);

  // f1 for run of 4: row py, cols px0..px0+3
  const int py  = tid >> 3;
  const int px0 = (tid & 7) << 2;
  float f1r[3][4] = {};
  #pragma unroll
  for (int ci = 0; ci < 3; ++ci) {
    float win[3][6];
    #pragma unroll
    for (int ky = 0; ky < 3; ++ky) {
      const float* base = &s_ov[(ci * X1R + py + ky) * X1S + px0];
      const float4 a  = *reinterpret_cast<const float4*>(base);
      const float2 b2 = *reinterpret_cast<const float2*>(base + 4);
      win[ky][0] = a.x; win[ky][1] = a.y; win[ky][2] = a.z; win[ky][3] = a.w;
      win[ky][4] = b2.x; win[ky][5] = b2.y;
    }
    #pragma unroll
    for (int co = 0; co < 3; ++co)
      #pragma unroll
      for (int ky = 0; ky < 3; ++ky)
        #pragma unroll
        for (int kx = 0; kx < 3; ++kx) {
          const float w = cw[((co * 3 + ci) * 3 + ky) * 3 + kx];
          #pragma unroll
          for (int j = 0; j < 4; ++j)
            f1r[co][j] += w * win[ky][j + kx];
        }
  }
  __syncthreads();   // all reads of s_ov-as-x1 / s_x2 done

  // ---- phase C: write f2 regs into s_ov overlay ----
  {
    const int col0 = (tid % 9) * 4;
    const int r    = tid / 9;
    #pragma unroll
    for (int co = 0; co < 3; ++co)
      *reinterpret_cast<float4*>(&s_ov[(co * F2R + r) * F2S + col0]) =
          make_float4(acc0[co][0], acc0[co][1], acc0[co][2], acc0[co][3]);
  }
  if (tid < 324 - 256) {
    const int run  = tid + 256;
    const int col0 = (run % 9) * 4;
    const int r    = run / 9;
    #pragma unroll
    for (int co = 0; co < 3; ++co)
      *reinterpret_cast<float4*>(&s_ov[(co * F2R + r) * F2S + col0]) =
          make_float4(acc1[co][0], acc1[co][1], acc1[co][2], acc1[co][3]);
  }
  __syncthreads();   // f2 tile ready

  // ---- correlation + nontemporal dwordx4 stores ----
  float* outp = out + ((size_t)bi * 9 * HH + (oy0 + py)) * WW + ox0 + px0;
  #pragma unroll
  for (int dyi = 0; dyi < 3; ++dyi) {
    float rv[3][8];
    #pragma unroll
    for (int c = 0; c < 3; ++c) {
      const float* base = &s_ov[(c * F2R + py + dyi * 2) * F2S + px0];
      const float4 a = *reinterpret_cast<const float4*>(base);
      const float4 b = *reinterpret_cast<const float4*>(base + 4);
      rv[c][0] = a.x; rv[c][1] = a.y; rv[c][2] = a.z; rv[c][3] = a.w;
      rv[c][4] = b.x; rv[c][5] = b.y; rv[c][6] = b.z; rv[c][7] = b.w;
    }
    #pragma unroll
    for (int dxi = 0; dxi < 3; ++dxi) {
      const int s = dxi * 2;
      f32x4 o;
      o.x = (f1r[0][0]*rv[0][s+0] + f1r[1][0]*rv[1][s+0] + f1r[2][0]*rv[2][s+0]) * (1.f/3.f);
      o.y = (f1r[0][1]*rv[0][s+1] + f1r[1][1]*rv[1][s+1] + f1r[2][1]*rv[2][s+1]) * (1.f/3.f);
      o.z = (f1r[0][2]*rv[0][s+2] + f1r[1][2]*rv[1][s+2] + f1r[2][2]*rv[2][s+2]) * (1.f/3.f);
      o.w = (f1r[0][3]*rv[0][s+3] + f1r[1][3]*rv[1][s+3] + f1r[2][3]*rv[2][s+3]) * (1.f/3.f);
      __builtin_nontemporal_store(o,
          reinterpret_cast<f32x4*>(outp + (size_t)(dyi * 3 + dxi) * HH * WW));
    }
  }
}

extern "C" void kernel_launch(void* const* d_in, const int* in_sizes, int n_in,
                              void* d_out, int out_size, void* d_ws, size_t ws_size,
                              hipStream_t stream) {
  const float* x1 = (const float*)d_in[0];
  const float* x2 = (const float*)d_in[1];
  const float* cw = (const float*)d_in[2];
  float* out = (float*)d_out;

  flownetc_fused_kernel<<<dim3(4096), 256, 0, stream>>>(x1, x2, cw, out);
}